// Round 13
// baseline (180.054 us; speedup 1.0000x reference)
//
#include <hip/hip_runtime.h>
#include <stdint.h>

#define NB 4
#define CC 256
#define C16 16
#define HH 64
#define WW 64
#define NN 4096

typedef __attribute__((ext_vector_type(8))) short short8;
typedef __attribute__((ext_vector_type(4))) float floatx4;
typedef __attribute__((ext_vector_type(16))) float floatx16;

#if __has_builtin(__builtin_amdgcn_exp2f)
#define EXP2(x) __builtin_amdgcn_exp2f(x)
#else
#define EXP2(x) exp2f(x)
#endif

__device__ __forceinline__ unsigned short f2bf(float f) {
    union { float f; unsigned u; } v; v.f = f;
    unsigned r = v.u + 0x7fffu + ((v.u >> 16) & 1u);
    return (unsigned short)(r >> 16);
}
__device__ __forceinline__ float bf2f(unsigned short h) {
    union { unsigned u; float f; } v; v.u = (unsigned)h << 16;
    return v.f;
}

// Fragment-major layouts (frag = 32 rows x 16 k = 64 lanes x 8 bf16 = 1KB):
//   qb/kb: frag f = b*128 + (n>>5); addr = f*512 + (n&31 + 32*(o>>3))*8 + (o&7)
//   vb:    frag f = (b*8 + (c>>5))*256 + (n>>4); addr = f*512 + (c&31 + 32*((n>>3)&1))*8 + (n&7)

// ========== K1: cast x->xT bf16 [b][n][c] (vectorized); cast wv/wq/wk; zero nu2 ==========
__global__ __launch_bounds__(256) void prep_kernel(
        const float* __restrict__ x, const float* __restrict__ wv,
        const float* __restrict__ wq, const float* __restrict__ wk,
        unsigned short* __restrict__ xT, unsigned short* __restrict__ wvb,
        unsigned short* __restrict__ wqkb, float* __restrict__ nu2) {
    int bid = blockIdx.x;
    if (bid < 1024) {
        __shared__ float tile_t[64][65];   // [n-local][c-local], pad 65: 2-way free
        int nt = bid & 63, ct = (bid >> 6) & 3, b = bid >> 8;
        int n0 = nt * 64, c0 = ct * 64;
        int tid = threadIdx.x;
        int rg = tid >> 4, f = tid & 15;
        const float* xb = x + ((size_t)b * CC + c0) * NN + n0;
#pragma unroll
        for (int p = 0; p < 4; ++p) {
            int c = p * 16 + rg;
            float4 v = *(const float4*)(xb + (size_t)c * NN + f * 4);
            tile_t[f * 4 + 0][c] = v.x;
            tile_t[f * 4 + 1][c] = v.y;
            tile_t[f * 4 + 2][c] = v.z;
            tile_t[f * 4 + 3][c] = v.w;
        }
        __syncthreads();
        unsigned short* xtb = xT + ((size_t)b * NN + n0) * CC + c0;
#pragma unroll
        for (int p = 0; p < 4; ++p) {
            int n = p * 16 + rg;
            ushort4 st;
            st.x = f2bf(tile_t[n][f * 4 + 0]);
            st.y = f2bf(tile_t[n][f * 4 + 1]);
            st.z = f2bf(tile_t[n][f * 4 + 2]);
            st.w = f2bf(tile_t[n][f * 4 + 3]);
            *(ushort4*)(xtb + (size_t)n * CC + f * 4) = st;
        }
    } else {
        int idx = (bid - 1024) * 256 + threadIdx.x;
        if (bid == 1024 && threadIdx.x < 128) nu2[threadIdx.x] = 0.f;
        if (idx < 16384) {
            float4 v = *(const float4*)(wv + idx * 4);
            ushort4 o;
            o.x = f2bf(v.x); o.y = f2bf(v.y); o.z = f2bf(v.z); o.w = f2bf(v.w);
            *(ushort4*)(wvb + idx * 4) = o;
        } else if (idx < 16384 + 6144) {
            int base = (idx - 16384) * 4;
#pragma unroll
            for (int u = 0; u < 4; ++u) {
                int e = base + u;
                int t = e / 12288;
                int i = e - t * 12288;
                int tap = i >> 12, o = (i >> 8) & 15, c = i & 255;
                const float* src = t ? wk : wq;
                wqkb[e] = f2bf(src[o * 768 + c * 3 + tap]);
            }
        }
    }
}

// ========== K2: conv_v (0..511) + conv_qk w/ FRN-ssq atomics (512..767) ==========
__global__ __launch_bounds__(256) void conv_kernel(
        const unsigned short* __restrict__ xT, const unsigned short* __restrict__ wvb,
        const unsigned short* __restrict__ wqkb, const float* __restrict__ bv,
        const float* __restrict__ bq, const float* __restrict__ bk,
        unsigned short* __restrict__ vb, unsigned short* __restrict__ qrawh,
        unsigned short* __restrict__ krawh, float* __restrict__ nu2) {
    int bid = blockIdx.x;
    int tid = threadIdx.x;
    int wv_ = tid >> 6, lane = tid & 63;
    int q16 = lane >> 4, c16 = lane & 15;
    if (bid < 512) {
        int ntile = bid & 63, b = (bid >> 6) & 3, ch = bid >> 8;
        int n0 = ntile * 64;
        int cb = ch * 128 + wv_ * 32;
        floatx4 fzero = {0.f, 0.f, 0.f, 0.f};
        floatx4 acc[2][4];
        for (int ct = 0; ct < 2; ++ct)
            for (int nt = 0; nt < 4; ++nt) acc[ct][nt] = fzero;
        const unsigned short* xb = xT + ((size_t)b * NN + n0) * CC;
        for (int kc = 0; kc < 8; ++kc) {
            int ko = kc * 32 + q16 * 8;
            short8 a0 = *(const short8*)(wvb + (size_t)(cb + c16) * CC + ko);
            short8 a1 = *(const short8*)(wvb + (size_t)(cb + 16 + c16) * CC + ko);
            short8 bf[4];
#pragma unroll
            for (int nt = 0; nt < 4; ++nt)
                bf[nt] = *(const short8*)(xb + (size_t)(nt * 16 + c16) * CC + ko);
#pragma unroll
            for (int nt = 0; nt < 4; ++nt) {
                acc[0][nt] = __builtin_amdgcn_mfma_f32_16x16x32_bf16(bf[nt], a0, acc[0][nt], 0, 0, 0);
                acc[1][nt] = __builtin_amdgcn_mfma_f32_16x16x32_bf16(bf[nt], a1, acc[1][nt], 0, 0, 0);
            }
        }
        // C: row = q16*4+r -> n-local, col = c16 -> c-local. ushort4 frag-major stores.
        float bv0 = bv[cb + c16], bv1 = bv[cb + 16 + c16];
        int off = 32 * 8 * (q16 >> 1) + (q16 & 1) * 4 + c16 * 8;
#pragma unroll
        for (int ct = 0; ct < 2; ++ct) {
            float bvv = ct ? bv1 : bv0;
#pragma unroll
            for (int nt = 0; nt < 4; ++nt) {
                size_t fb = (((size_t)b * 8 + ch * 4 + wv_) * 256 + (n0 >> 4) + nt) * 512;
                ushort4 st;
                st.x = f2bf(acc[ct][nt][0] + bvv);
                st.y = f2bf(acc[ct][nt][1] + bvv);
                st.z = f2bf(acc[ct][nt][2] + bvv);
                st.w = f2bf(acc[ct][nt][3] + bvv);
                *(ushort4*)(vb + fb + off + ct * 16 * 8) = st;
            }
        }
    } else {
        int cv = bid - 512;
        int nb2 = cv & 63, b = cv >> 6;
        int nl = nb2 * 64 + wv_ * 16 + c16;     // load-n (A-frag m index)
        int h = nl >> 6, w = nl & 63;
        bool vm1 = (w != 0), vp1 = (w != 63);
        bool vm64 = (h != 0), vp64 = (h != 63);
        short8 zero8 = {0, 0, 0, 0, 0, 0, 0, 0};
        floatx4 accq = {0.f, 0.f, 0.f, 0.f}, acck = {0.f, 0.f, 0.f, 0.f};
        const unsigned short* xb = xT + (size_t)b * NN * CC;
        const unsigned short* wrow = wqkb + c16 * 256;
        for (int kc = 0; kc < 8; ++kc) {
            int ko = kc * 32 + q16 * 8;
            short8 b0 = *(const short8*)(xb + (size_t)nl * CC + ko);
            short8 bm1 = vm1 ? *(const short8*)(xb + (size_t)(nl - 1) * CC + ko) : zero8;
            short8 bp1 = vp1 ? *(const short8*)(xb + (size_t)(nl + 1) * CC + ko) : zero8;
            short8 bm64 = vm64 ? *(const short8*)(xb + (size_t)(nl - 64) * CC + ko) : zero8;
            short8 bp64 = vp64 ? *(const short8*)(xb + (size_t)(nl + 64) * CC + ko) : zero8;
            short8 aq0 = *(const short8*)(wrow + 0 * 4096 + ko);
            short8 aq1 = *(const short8*)(wrow + 1 * 4096 + ko);
            short8 aq2 = *(const short8*)(wrow + 2 * 4096 + ko);
            short8 ak0 = *(const short8*)(wrow + 12288 + 0 * 4096 + ko);
            short8 ak1 = *(const short8*)(wrow + 12288 + 1 * 4096 + ko);
            short8 ak2 = *(const short8*)(wrow + 12288 + 2 * 4096 + ko);
            accq = __builtin_amdgcn_mfma_f32_16x16x32_bf16(bm1, aq0, accq, 0, 0, 0);
            accq = __builtin_amdgcn_mfma_f32_16x16x32_bf16(b0, aq1, accq, 0, 0, 0);
            accq = __builtin_amdgcn_mfma_f32_16x16x32_bf16(bp1, aq2, accq, 0, 0, 0);
            acck = __builtin_amdgcn_mfma_f32_16x16x32_bf16(bm64, ak0, acck, 0, 0, 0);
            acck = __builtin_amdgcn_mfma_f32_16x16x32_bf16(b0, ak1, acck, 0, 0, 0);
            acck = __builtin_amdgcn_mfma_f32_16x16x32_bf16(bp64, ak2, acck, 0, 0, 0);
        }
        // C: row = q16*4+r -> n, col = c16 -> o. bf16 ushort4 stores.
        int nst = nb2 * 64 + wv_ * 16 + q16 * 4;
        float bqv = bq[c16], bkv = bk[c16];
        ushort4 sq4, sk4;
        float ssq = 0.f, ssk = 0.f;
        {
            float vq0 = accq[0] + bqv, vq1 = accq[1] + bqv, vq2 = accq[2] + bqv, vq3 = accq[3] + bqv;
            float vk0 = acck[0] + bkv, vk1 = acck[1] + bkv, vk2 = acck[2] + bkv, vk3 = acck[3] + bkv;
            sq4.x = f2bf(vq0); sq4.y = f2bf(vq1); sq4.z = f2bf(vq2); sq4.w = f2bf(vq3);
            sk4.x = f2bf(vk0); sk4.y = f2bf(vk1); sk4.z = f2bf(vk2); sk4.w = f2bf(vk3);
            ssq = vq0 * vq0 + vq1 * vq1 + vq2 * vq2 + vq3 * vq3;
            ssk = vk0 * vk0 + vk1 * vk1 + vk2 * vk2 + vk3 * vk3;
        }
        *(ushort4*)(qrawh + (size_t)(b * C16 + c16) * NN + nst) = sq4;
        *(ushort4*)(krawh + (size_t)(b * C16 + c16) * NN + nst) = sk4;
        ssq += __shfl_xor(ssq, 16, 64);
        ssq += __shfl_xor(ssq, 32, 64);
        ssk += __shfl_xor(ssk, 16, 64);
        ssk += __shfl_xor(ssk, 32, 64);
        if (lane < 16) {
            atomicAdd(nu2 + b * C16 + lane, ssq);
            atomicAdd(nu2 + 64 + b * C16 + lane, ssk);
        }
    }
}

// ========== K3: FRN + Mish (bf16 input), frag-major out; 512 blocks, 4 ch/thread ==========
// q additionally scaled by log2(e) so attention can use exp2.
__global__ __launch_bounds__(256) void frn_mish_kernel(
        const unsigned short* __restrict__ qrawh, const unsigned short* __restrict__ krawh,
        const float* __restrict__ nu2, const float* __restrict__ eps_q,
        const float* __restrict__ eps_k, unsigned short* __restrict__ qb,
        unsigned short* __restrict__ kb) {
    int blk = blockIdx.x;                 // 512 = tensor(2) x b(4) x nchunk(64)
    int tensor = blk >> 8;
    int b = (blk >> 6) & 3;
    int nch = blk & 63;
    const unsigned short* raw = tensor ? krawh : qrawh;
    const float* eps = tensor ? eps_k : eps_q;
    unsigned short* outp = tensor ? kb : qb;
    const float* nu = nu2 + tensor * 64 + b * C16;
    float scale = tensor ? 1.0f : 1.44269504f;
    int n = nch * 64 + (threadIdx.x & 63);
    int oq = threadIdx.x >> 6;            // 0..3 -> channels oq*4..oq*4+3
    ushort4 pk4;
#pragma unroll
    for (int i = 0; i < 4; ++i) {
        int o = oq * 4 + i;
        float r = bf2f(raw[(size_t)(b * C16 + o) * NN + n]);
        float v = r * rsqrtf(nu[o] * (1.f / (float)NN) + fabsf(eps[o]));
        float sp = fmaxf(v, 0.f) + log1pf(expf(-fabsf(v)));   // stable softplus
        float m = v * tanhf(sp) * scale;
        ((unsigned short*)&pk4)[i] = f2bf(m);
    }
    size_t base = ((size_t)b * 128 + (n >> 5)) * 512 + (size_t)(n & 31) * 8
                + (size_t)(oq >> 1) * 256 + (oq & 1) * 4;
    *(ushort4*)(outp + base) = pk4;
}

// exp2 (NO shift — softmax is shift-invariant; S range fits f32/bf16 exponent span)
// + pack to bf16 A-frags (half-lane exchange); lsum accumulated in f32 pre-rounding.
__device__ __forceinline__ void pack_p0(
        floatx16 sc, bool hi, short8* A0, short8* A1, float* lsum) {
    unsigned pk[8];
    float ls = 0.f;
#pragma unroll
    for (int p = 0; p < 8; ++p) {
        float e0 = EXP2(sc[2 * p]);
        float e1 = EXP2(sc[2 * p + 1]);
        ls += e0 + e1;
        pk[p] = __builtin_amdgcn_perm(__float_as_uint(e1), __float_as_uint(e0), 0x07060302u);
    }
    *lsum += ls;
    unsigned xk[8];
#pragma unroll
    for (int p = 0; p < 8; ++p) xk[p] = (unsigned)__shfl_xor((int)pk[p], 32, 64);
    union { unsigned u[4]; short8 s; } a0, a1;
    a0.u[0] = hi ? xk[2] : pk[0]; a0.u[1] = hi ? xk[3] : pk[1];
    a0.u[2] = hi ? pk[2] : xk[0]; a0.u[3] = hi ? pk[3] : xk[1];
    a1.u[0] = hi ? xk[6] : pk[4]; a1.u[1] = hi ? xk[7] : pk[5];
    a1.u[2] = hi ? pk[6] : xk[4]; a1.u[3] = hi ? pk[7] : xk[5];
    *A0 = a0.s; *A1 = a1.s;
}

// ========== K4: attention, j=32 c=128 per block, 4-way k-split waves ==========
// grid 1024: cs = id&1 (128-c), b = (id>>1)&3, jt = id>>3 (32-j tile).
// 3 blocks/CU target. Wave w owns k in [1024w, 1024w+1024), 32 steps of 32k.
// acc = 4 x floatx16 (64 AGPR) -> 3 waves/SIMD fits the register file.
__global__ __launch_bounds__(256, 3) void attn_kernel(
        const unsigned short* __restrict__ qb, const unsigned short* __restrict__ kb,
        const unsigned short* __restrict__ vb, const float* __restrict__ x,
        const float* __restrict__ gamma_p, float* __restrict__ out) {
    __shared__ float lpart[4][32];
    __shared__ float obuf[4][32][33];

    int tid = threadIdx.x;
    int wv_ = __builtin_amdgcn_readfirstlane(tid >> 6);   // k-quarter
    int lane = tid & 63;
    int l31 = lane & 31, lh = lane >> 5;
    bool hi = (lh != 0);
    int id = blockIdx.x;
    int cs = id & 1, b = (id >> 1) & 3, jt = id >> 3;     // jt 0..127
    int jbase = jt * 32, cb = cs * 128;
    int lane8 = lane * 8;

    const unsigned short* qfp = qb + ((size_t)b * 128 + jt) * 512 + lane8;
    const unsigned short* kfb = kb + ((size_t)b * 128 + wv_ * 32) * 512 + lane8;

    short8 qf = *(const short8*)qfp;

    floatx16 z16 = {0,0,0,0,0,0,0,0,0,0,0,0,0,0,0,0};
    floatx16 acc[4];
#pragma unroll
    for (int cg = 0; cg < 4; ++cg) acc[cg] = z16;
    float lsum = 0.f;

    const unsigned short* vp0 = vb + (((size_t)b * 8 + cs * 4 + 0) * 256 + wv_ * 64) * 512 + lane8;
    const unsigned short* vp1 = vb + (((size_t)b * 8 + cs * 4 + 1) * 256 + wv_ * 64) * 512 + lane8;
    const unsigned short* vp2 = vb + (((size_t)b * 8 + cs * 4 + 2) * 256 + wv_ * 64) * 512 + lane8;
    const unsigned short* vp3 = vb + (((size_t)b * 8 + cs * 4 + 3) * 256 + wv_ * 64) * 512 + lane8;

    short8 ak = *(const short8*)kfb;
#pragma unroll 1
    for (int step = 0; step < 32; ++step) {
        short8 vf0a = *(const short8*)vp0, vf0b = *(const short8*)(vp0 + 512);
        short8 vf1a = *(const short8*)vp1, vf1b = *(const short8*)(vp1 + 512);
        short8 vf2a = *(const short8*)vp2, vf2b = *(const short8*)(vp2 + 512);
        short8 vf3a = *(const short8*)vp3, vf3b = *(const short8*)(vp3 + 512);
        floatx16 sc = __builtin_amdgcn_mfma_f32_32x32x16_bf16(ak, qf, z16, 0, 0, 0);
        ak = *(const short8*)(kfb + (size_t)((step + 1) & 31) * 512);
        short8 A0, A1;
        pack_p0(sc, hi, &A0, &A1, &lsum);
        acc[0] = __builtin_amdgcn_mfma_f32_32x32x16_bf16(A0, vf0a, acc[0], 0, 0, 0);
        acc[0] = __builtin_amdgcn_mfma_f32_32x32x16_bf16(A1, vf0b, acc[0], 0, 0, 0);
        acc[1] = __builtin_amdgcn_mfma_f32_32x32x16_bf16(A0, vf1a, acc[1], 0, 0, 0);
        acc[1] = __builtin_amdgcn_mfma_f32_32x32x16_bf16(A1, vf1b, acc[1], 0, 0, 0);
        acc[2] = __builtin_amdgcn_mfma_f32_32x32x16_bf16(A0, vf2a, acc[2], 0, 0, 0);
        acc[2] = __builtin_amdgcn_mfma_f32_32x32x16_bf16(A1, vf2b, acc[2], 0, 0, 0);
        acc[3] = __builtin_amdgcn_mfma_f32_32x32x16_bf16(A0, vf3a, acc[3], 0, 0, 0);
        acc[3] = __builtin_amdgcn_mfma_f32_32x32x16_bf16(A1, vf3b, acc[3], 0, 0, 0);
        vp0 += 1024; vp1 += 1024; vp2 += 1024; vp3 += 1024;
    }

    // l: combine lane halves (disjoint kcol rows), then sum the 4 k-quarters
    lsum += __shfl_xor(lsum, 32, 64);
    if (lh == 0) lpart[wv_][l31] = lsum;
    __syncthreads();

    int j31r = tid & 31;
    int cgrp = tid >> 5;   // 0..7 -> 4 c-rows each
    float gl = gamma_p[0] /
               (lpart[0][j31r] + lpart[1][j31r] + lpart[2][j31r] + lpart[3][j31r]);
    const float* xbb = x + (size_t)b * CC * NN;
    float* obb = out + (size_t)b * CC * NN;
    int hofs = lh * 4;
    // O reduction over the 4 k-quarter waves, one cg (32c) tile at a time.
    // acc C-layout: col(lane&31)=c-local, row=j-local; write obuf[w][j][c], read obuf[w][j31][c]
#pragma unroll
    for (int cg = 0; cg < 4; ++cg) {
        __syncthreads();
#pragma unroll
        for (int r = 0; r < 16; ++r) {
            int row = (r & 3) + 8 * (r >> 2) + hofs;
            obuf[wv_][row][l31] = acc[cg][r];
        }
        __syncthreads();
#pragma unroll
        for (int i = 0; i < 4; ++i) {
            int c = cgrp * 4 + i;
            float val = obuf[0][j31r][c] + obuf[1][j31r][c] + obuf[2][j31r][c] + obuf[3][j31r][c];
            size_t oidx = (size_t)(cb + cg * 32 + c) * NN + jbase + j31r;
            obb[oidx] = fmaf(gl, val, xbb[oidx]);
        }
    }
}

extern "C" void kernel_launch(void* const* d_in, const int* in_sizes, int n_in,
                              void* d_out, int out_size, void* d_ws, size_t ws_size,
                              hipStream_t stream) {
    const float* x     = (const float*)d_in[0];
    const float* wq    = (const float*)d_in[1];
    const float* bq    = (const float*)d_in[2];
    const float* wk    = (const float*)d_in[3];
    const float* bk    = (const float*)d_in[4];
    const float* wv    = (const float*)d_in[5];
    const float* bv    = (const float*)d_in[6];
    const float* gamma = (const float*)d_in[7];
    const float* eps_q = (const float*)d_in[8];
    const float* eps_k = (const float*)d_in[9];
    float* out = (float*)d_out;

    char* ws = (char*)d_ws;
    unsigned short* qrawh = (unsigned short*)ws;                     // 512 KB (1 MB slot)
    unsigned short* krawh = (unsigned short*)(ws + (1u << 20));      // 512 KB (1 MB slot)
    float* nu2  = (float*)(ws + (2u << 20));                         // 512 B
    unsigned short* qb = (unsigned short*)(ws + (2u << 20) + 4096);  // 512 KB
    unsigned short* kb = qb + (size_t)NB * NN * C16;                 // 512 KB
    unsigned short* vb = kb + (size_t)NB * NN * C16;                 // 8 MB
    unsigned short* xT = vb + (size_t)NB * CC * NN;                  // 8 MB
    unsigned short* wvb = xT + (size_t)NB * NN * CC;                 // 128 KB
    unsigned short* wqkb = wvb + (size_t)CC * CC;                    // 48 KB

    prep_kernel<<<dim3(1112), dim3(256), 0, stream>>>(x, wv, wq, wk, xT, wvb, wqkb, nu2);
    conv_kernel<<<dim3(768), dim3(256), 0, stream>>>(xT, wvb, wqkb, bv, bq, bk, vb, qrawh, krawh, nu2);
    frn_mish_kernel<<<dim3(512), dim3(256), 0, stream>>>(qrawh, krawh, nu2, eps_q, eps_k, qb, kb);
    attn_kernel<<<dim3(1024), dim3(256), 0, stream>>>(qb, kb, vb, x, gamma, out);
}

// Round 14
// 166.976 us; speedup vs baseline: 1.0783x; 1.0783x over previous
//
#include <hip/hip_runtime.h>
#include <stdint.h>

#define NB 4
#define CC 256
#define C16 16
#define HH 64
#define WW 64
#define NN 4096

typedef __attribute__((ext_vector_type(8))) short short8;
typedef __attribute__((ext_vector_type(4))) float floatx4;
typedef __attribute__((ext_vector_type(16))) float floatx16;

#if __has_builtin(__builtin_amdgcn_exp2f)
#define EXP2(x) __builtin_amdgcn_exp2f(x)
#else
#define EXP2(x) exp2f(x)
#endif

__device__ __forceinline__ unsigned short f2bf(float f) {
    union { float f; unsigned u; } v; v.f = f;
    unsigned r = v.u + 0x7fffu + ((v.u >> 16) & 1u);
    return (unsigned short)(r >> 16);
}
__device__ __forceinline__ float bf2f(unsigned short h) {
    union { unsigned u; float f; } v; v.u = (unsigned)h << 16;
    return v.f;
}

// Fragment-major layouts (frag = 32 rows x 16 k = 64 lanes x 8 bf16 = 1KB):
//   qb/kb: frag f = b*128 + (n>>5); addr = f*512 + (n&31 + 32*(o>>3))*8 + (o&7)
//   vb:    frag f = (b*8 + (c>>5))*256 + (n>>4); addr = f*512 + (c&31 + 32*((n>>3)&1))*8 + (n&7)

// ========== K1: cast x->xT bf16 [b][n][c] (vectorized); cast wv/wq/wk; zero nu2 ==========
__global__ __launch_bounds__(256) void prep_kernel(
        const float* __restrict__ x, const float* __restrict__ wv,
        const float* __restrict__ wq, const float* __restrict__ wk,
        unsigned short* __restrict__ xT, unsigned short* __restrict__ wvb,
        unsigned short* __restrict__ wqkb, float* __restrict__ nu2) {
    int bid = blockIdx.x;
    if (bid < 1024) {
        __shared__ float tile_t[64][65];   // [n-local][c-local], pad 65: 2-way free
        int nt = bid & 63, ct = (bid >> 6) & 3, b = bid >> 8;
        int n0 = nt * 64, c0 = ct * 64;
        int tid = threadIdx.x;
        int rg = tid >> 4, f = tid & 15;
        const float* xb = x + ((size_t)b * CC + c0) * NN + n0;
#pragma unroll
        for (int p = 0; p < 4; ++p) {
            int c = p * 16 + rg;
            float4 v = *(const float4*)(xb + (size_t)c * NN + f * 4);
            tile_t[f * 4 + 0][c] = v.x;
            tile_t[f * 4 + 1][c] = v.y;
            tile_t[f * 4 + 2][c] = v.z;
            tile_t[f * 4 + 3][c] = v.w;
        }
        __syncthreads();
        unsigned short* xtb = xT + ((size_t)b * NN + n0) * CC + c0;
#pragma unroll
        for (int p = 0; p < 4; ++p) {
            int n = p * 16 + rg;
            ushort4 st;
            st.x = f2bf(tile_t[n][f * 4 + 0]);
            st.y = f2bf(tile_t[n][f * 4 + 1]);
            st.z = f2bf(tile_t[n][f * 4 + 2]);
            st.w = f2bf(tile_t[n][f * 4 + 3]);
            *(ushort4*)(xtb + (size_t)n * CC + f * 4) = st;
        }
    } else {
        int idx = (bid - 1024) * 256 + threadIdx.x;
        if (bid == 1024 && threadIdx.x < 128) nu2[threadIdx.x] = 0.f;
        if (idx < 16384) {
            float4 v = *(const float4*)(wv + idx * 4);
            ushort4 o;
            o.x = f2bf(v.x); o.y = f2bf(v.y); o.z = f2bf(v.z); o.w = f2bf(v.w);
            *(ushort4*)(wvb + idx * 4) = o;
        } else if (idx < 16384 + 6144) {
            int base = (idx - 16384) * 4;
#pragma unroll
            for (int u = 0; u < 4; ++u) {
                int e = base + u;
                int t = e / 12288;
                int i = e - t * 12288;
                int tap = i >> 12, o = (i >> 8) & 15, c = i & 255;
                const float* src = t ? wk : wq;
                wqkb[e] = f2bf(src[o * 768 + c * 3 + tap]);
            }
        }
    }
}

// ========== K2: conv_v (0..511) + conv_qk w/ FRN-ssq atomics (512..767) ==========
__global__ __launch_bounds__(256) void conv_kernel(
        const unsigned short* __restrict__ xT, const unsigned short* __restrict__ wvb,
        const unsigned short* __restrict__ wqkb, const float* __restrict__ bv,
        const float* __restrict__ bq, const float* __restrict__ bk,
        unsigned short* __restrict__ vb, unsigned short* __restrict__ qrawh,
        unsigned short* __restrict__ krawh, float* __restrict__ nu2) {
    int bid = blockIdx.x;
    int tid = threadIdx.x;
    int wv_ = tid >> 6, lane = tid & 63;
    int q16 = lane >> 4, c16 = lane & 15;
    if (bid < 512) {
        int ntile = bid & 63, b = (bid >> 6) & 3, ch = bid >> 8;
        int n0 = ntile * 64;
        int cb = ch * 128 + wv_ * 32;
        floatx4 fzero = {0.f, 0.f, 0.f, 0.f};
        floatx4 acc[2][4];
        for (int ct = 0; ct < 2; ++ct)
            for (int nt = 0; nt < 4; ++nt) acc[ct][nt] = fzero;
        const unsigned short* xb = xT + ((size_t)b * NN + n0) * CC;
        for (int kc = 0; kc < 8; ++kc) {
            int ko = kc * 32 + q16 * 8;
            short8 a0 = *(const short8*)(wvb + (size_t)(cb + c16) * CC + ko);
            short8 a1 = *(const short8*)(wvb + (size_t)(cb + 16 + c16) * CC + ko);
            short8 bf[4];
#pragma unroll
            for (int nt = 0; nt < 4; ++nt)
                bf[nt] = *(const short8*)(xb + (size_t)(nt * 16 + c16) * CC + ko);
#pragma unroll
            for (int nt = 0; nt < 4; ++nt) {
                acc[0][nt] = __builtin_amdgcn_mfma_f32_16x16x32_bf16(bf[nt], a0, acc[0][nt], 0, 0, 0);
                acc[1][nt] = __builtin_amdgcn_mfma_f32_16x16x32_bf16(bf[nt], a1, acc[1][nt], 0, 0, 0);
            }
        }
        // C: row = q16*4+r -> n-local, col = c16 -> c-local. ushort4 frag-major stores.
        float bv0 = bv[cb + c16], bv1 = bv[cb + 16 + c16];
        int off = 32 * 8 * (q16 >> 1) + (q16 & 1) * 4 + c16 * 8;
#pragma unroll
        for (int ct = 0; ct < 2; ++ct) {
            float bvv = ct ? bv1 : bv0;
#pragma unroll
            for (int nt = 0; nt < 4; ++nt) {
                size_t fb = (((size_t)b * 8 + ch * 4 + wv_) * 256 + (n0 >> 4) + nt) * 512;
                ushort4 st;
                st.x = f2bf(acc[ct][nt][0] + bvv);
                st.y = f2bf(acc[ct][nt][1] + bvv);
                st.z = f2bf(acc[ct][nt][2] + bvv);
                st.w = f2bf(acc[ct][nt][3] + bvv);
                *(ushort4*)(vb + fb + off + ct * 16 * 8) = st;
            }
        }
    } else {
        int cv = bid - 512;
        int nb2 = cv & 63, b = cv >> 6;
        int nl = nb2 * 64 + wv_ * 16 + c16;     // load-n (A-frag m index)
        int h = nl >> 6, w = nl & 63;
        bool vm1 = (w != 0), vp1 = (w != 63);
        bool vm64 = (h != 0), vp64 = (h != 63);
        short8 zero8 = {0, 0, 0, 0, 0, 0, 0, 0};
        floatx4 accq = {0.f, 0.f, 0.f, 0.f}, acck = {0.f, 0.f, 0.f, 0.f};
        const unsigned short* xb = xT + (size_t)b * NN * CC;
        const unsigned short* wrow = wqkb + c16 * 256;
        for (int kc = 0; kc < 8; ++kc) {
            int ko = kc * 32 + q16 * 8;
            short8 b0 = *(const short8*)(xb + (size_t)nl * CC + ko);
            short8 bm1 = vm1 ? *(const short8*)(xb + (size_t)(nl - 1) * CC + ko) : zero8;
            short8 bp1 = vp1 ? *(const short8*)(xb + (size_t)(nl + 1) * CC + ko) : zero8;
            short8 bm64 = vm64 ? *(const short8*)(xb + (size_t)(nl - 64) * CC + ko) : zero8;
            short8 bp64 = vp64 ? *(const short8*)(xb + (size_t)(nl + 64) * CC + ko) : zero8;
            short8 aq0 = *(const short8*)(wrow + 0 * 4096 + ko);
            short8 aq1 = *(const short8*)(wrow + 1 * 4096 + ko);
            short8 aq2 = *(const short8*)(wrow + 2 * 4096 + ko);
            short8 ak0 = *(const short8*)(wrow + 12288 + 0 * 4096 + ko);
            short8 ak1 = *(const short8*)(wrow + 12288 + 1 * 4096 + ko);
            short8 ak2 = *(const short8*)(wrow + 12288 + 2 * 4096 + ko);
            accq = __builtin_amdgcn_mfma_f32_16x16x32_bf16(bm1, aq0, accq, 0, 0, 0);
            accq = __builtin_amdgcn_mfma_f32_16x16x32_bf16(b0, aq1, accq, 0, 0, 0);
            accq = __builtin_amdgcn_mfma_f32_16x16x32_bf16(bp1, aq2, accq, 0, 0, 0);
            acck = __builtin_amdgcn_mfma_f32_16x16x32_bf16(bm64, ak0, acck, 0, 0, 0);
            acck = __builtin_amdgcn_mfma_f32_16x16x32_bf16(b0, ak1, acck, 0, 0, 0);
            acck = __builtin_amdgcn_mfma_f32_16x16x32_bf16(bp64, ak2, acck, 0, 0, 0);
        }
        // C: row = q16*4+r -> n, col = c16 -> o. bf16 ushort4 stores.
        int nst = nb2 * 64 + wv_ * 16 + q16 * 4;
        float bqv = bq[c16], bkv = bk[c16];
        ushort4 sq4, sk4;
        float ssq = 0.f, ssk = 0.f;
        {
            float vq0 = accq[0] + bqv, vq1 = accq[1] + bqv, vq2 = accq[2] + bqv, vq3 = accq[3] + bqv;
            float vk0 = acck[0] + bkv, vk1 = acck[1] + bkv, vk2 = acck[2] + bkv, vk3 = acck[3] + bkv;
            sq4.x = f2bf(vq0); sq4.y = f2bf(vq1); sq4.z = f2bf(vq2); sq4.w = f2bf(vq3);
            sk4.x = f2bf(vk0); sk4.y = f2bf(vk1); sk4.z = f2bf(vk2); sk4.w = f2bf(vk3);
            ssq = vq0 * vq0 + vq1 * vq1 + vq2 * vq2 + vq3 * vq3;
            ssk = vk0 * vk0 + vk1 * vk1 + vk2 * vk2 + vk3 * vk3;
        }
        *(ushort4*)(qrawh + (size_t)(b * C16 + c16) * NN + nst) = sq4;
        *(ushort4*)(krawh + (size_t)(b * C16 + c16) * NN + nst) = sk4;
        ssq += __shfl_xor(ssq, 16, 64);
        ssq += __shfl_xor(ssq, 32, 64);
        ssk += __shfl_xor(ssk, 16, 64);
        ssk += __shfl_xor(ssk, 32, 64);
        if (lane < 16) {
            atomicAdd(nu2 + b * C16 + lane, ssq);
            atomicAdd(nu2 + 64 + b * C16 + lane, ssk);
        }
    }
}

// ========== K3: FRN + Mish (bf16 input), frag-major out; 512 blocks, 4 ch/thread ==========
// q additionally scaled by log2(e) so attention can use exp2.
__global__ __launch_bounds__(256) void frn_mish_kernel(
        const unsigned short* __restrict__ qrawh, const unsigned short* __restrict__ krawh,
        const float* __restrict__ nu2, const float* __restrict__ eps_q,
        const float* __restrict__ eps_k, unsigned short* __restrict__ qb,
        unsigned short* __restrict__ kb) {
    int blk = blockIdx.x;                 // 512 = tensor(2) x b(4) x nchunk(64)
    int tensor = blk >> 8;
    int b = (blk >> 6) & 3;
    int nch = blk & 63;
    const unsigned short* raw = tensor ? krawh : qrawh;
    const float* eps = tensor ? eps_k : eps_q;
    unsigned short* outp = tensor ? kb : qb;
    const float* nu = nu2 + tensor * 64 + b * C16;
    float scale = tensor ? 1.0f : 1.44269504f;
    int n = nch * 64 + (threadIdx.x & 63);
    int oq = threadIdx.x >> 6;            // 0..3 -> channels oq*4..oq*4+3
    ushort4 pk4;
#pragma unroll
    for (int i = 0; i < 4; ++i) {
        int o = oq * 4 + i;
        float r = bf2f(raw[(size_t)(b * C16 + o) * NN + n]);
        float v = r * rsqrtf(nu[o] * (1.f / (float)NN) + fabsf(eps[o]));
        float sp = fmaxf(v, 0.f) + log1pf(expf(-fabsf(v)));   // stable softplus
        float m = v * tanhf(sp) * scale;
        ((unsigned short*)&pk4)[i] = f2bf(m);
    }
    size_t base = ((size_t)b * 128 + (n >> 5)) * 512 + (size_t)(n & 31) * 8
                + (size_t)(oq >> 1) * 256 + (oq & 1) * 4;
    *(ushort4*)(outp + base) = pk4;
}

// exp2 (NO shift — softmax shift-invariant, S range fits f32/bf16 exponent span)
// + pack to bf16 A-frags (half-lane exchange); lsum accumulated in f32 pre-rounding.
__device__ __forceinline__ void pack_p0(
        floatx16 sc, bool hi, short8* A0, short8* A1, float* lsum) {
    unsigned pk[8];
    float ls = 0.f;
#pragma unroll
    for (int p = 0; p < 8; ++p) {
        float e0 = EXP2(sc[2 * p]);
        float e1 = EXP2(sc[2 * p + 1]);
        ls += e0 + e1;
        pk[p] = __builtin_amdgcn_perm(__float_as_uint(e1), __float_as_uint(e0), 0x07060302u);
    }
    *lsum += ls;
    unsigned xk[8];
#pragma unroll
    for (int p = 0; p < 8; ++p) xk[p] = (unsigned)__shfl_xor((int)pk[p], 32, 64);
    union { unsigned u[4]; short8 s; } a0, a1;
    a0.u[0] = hi ? xk[2] : pk[0]; a0.u[1] = hi ? xk[3] : pk[1];
    a0.u[2] = hi ? pk[2] : xk[0]; a0.u[3] = hi ? pk[3] : xk[1];
    a1.u[0] = hi ? xk[6] : pk[4]; a1.u[1] = hi ? xk[7] : pk[5];
    a1.u[2] = hi ? pk[6] : xk[4]; a1.u[3] = hi ? pk[7] : xk[5];
    *A0 = a0.s; *A1 = a1.s;
}

// ========== K4: attention, j=32 c=256 per block (NO c-duplication of exp) ==========
// grid 512: b = id&3 (XCD-aligned -> per-XCD V slice 2MB L2-resident), jt = id>>2.
// 2 blocks/CU. Wave w owns k in [1024w, 1024w+1024), 32 steps of 32k.
// Per step: 1 QK MFMA + 1 pack (16 exps/lane) + 16 PV MFMA. acc = 8 x floatx16.
__global__ __launch_bounds__(256, 2) void attn_kernel(
        const unsigned short* __restrict__ qb, const unsigned short* __restrict__ kb,
        const unsigned short* __restrict__ vb, const float* __restrict__ x,
        const float* __restrict__ gamma_p, float* __restrict__ out) {
    __shared__ float lpart[4][32];
    __shared__ float obuf[4][32][33];

    int tid = threadIdx.x;
    int wv_ = __builtin_amdgcn_readfirstlane(tid >> 6);   // k-quarter
    int lane = tid & 63;
    int l31 = lane & 31, lh = lane >> 5;
    bool hi = (lh != 0);
    int id = blockIdx.x;
    int b = id & 3, jt = id >> 2;                          // jt 0..127
    int jbase = jt * 32;
    int lane8 = lane * 8;

    const unsigned short* qfp = qb + ((size_t)b * 128 + jt) * 512 + lane8;
    const unsigned short* kfb = kb + ((size_t)b * 128 + wv_ * 32) * 512 + lane8;

    short8 qf = *(const short8*)qfp;

    floatx16 z16 = {0,0,0,0,0,0,0,0,0,0,0,0,0,0,0,0};
    floatx16 acc[8];
#pragma unroll
    for (int cg = 0; cg < 8; ++cg) acc[cg] = z16;
    float lsum = 0.f;

    const unsigned short* vp[8];
#pragma unroll
    for (int cg = 0; cg < 8; ++cg)
        vp[cg] = vb + (((size_t)b * 8 + cg) * 256 + wv_ * 64) * 512 + lane8;

    short8 ak = *(const short8*)kfb;
#pragma unroll 1
    for (int step = 0; step < 32; ++step) {
        // first half of V loads (groups 0..3) — in flight across QK + pack
        short8 vfa0 = *(const short8*)vp[0], vfb0 = *(const short8*)(vp[0] + 512);
        short8 vfa1 = *(const short8*)vp[1], vfb1 = *(const short8*)(vp[1] + 512);
        short8 vfa2 = *(const short8*)vp[2], vfb2 = *(const short8*)(vp[2] + 512);
        short8 vfa3 = *(const short8*)vp[3], vfb3 = *(const short8*)(vp[3] + 512);
        floatx16 sc = __builtin_amdgcn_mfma_f32_32x32x16_bf16(ak, qf, z16, 0, 0, 0);
        ak = *(const short8*)(kfb + (size_t)((step + 1) & 31) * 512);
        short8 A0, A1;
        pack_p0(sc, hi, &A0, &A1, &lsum);
        // second half of V loads (groups 4..7) — covered by PV on groups 0..3
        short8 vfa4 = *(const short8*)vp[4], vfb4 = *(const short8*)(vp[4] + 512);
        short8 vfa5 = *(const short8*)vp[5], vfb5 = *(const short8*)(vp[5] + 512);
        short8 vfa6 = *(const short8*)vp[6], vfb6 = *(const short8*)(vp[6] + 512);
        short8 vfa7 = *(const short8*)vp[7], vfb7 = *(const short8*)(vp[7] + 512);
        acc[0] = __builtin_amdgcn_mfma_f32_32x32x16_bf16(A0, vfa0, acc[0], 0, 0, 0);
        acc[0] = __builtin_amdgcn_mfma_f32_32x32x16_bf16(A1, vfb0, acc[0], 0, 0, 0);
        acc[1] = __builtin_amdgcn_mfma_f32_32x32x16_bf16(A0, vfa1, acc[1], 0, 0, 0);
        acc[1] = __builtin_amdgcn_mfma_f32_32x32x16_bf16(A1, vfb1, acc[1], 0, 0, 0);
        acc[2] = __builtin_amdgcn_mfma_f32_32x32x16_bf16(A0, vfa2, acc[2], 0, 0, 0);
        acc[2] = __builtin_amdgcn_mfma_f32_32x32x16_bf16(A1, vfb2, acc[2], 0, 0, 0);
        acc[3] = __builtin_amdgcn_mfma_f32_32x32x16_bf16(A0, vfa3, acc[3], 0, 0, 0);
        acc[3] = __builtin_amdgcn_mfma_f32_32x32x16_bf16(A1, vfb3, acc[3], 0, 0, 0);
        acc[4] = __builtin_amdgcn_mfma_f32_32x32x16_bf16(A0, vfa4, acc[4], 0, 0, 0);
        acc[4] = __builtin_amdgcn_mfma_f32_32x32x16_bf16(A1, vfb4, acc[4], 0, 0, 0);
        acc[5] = __builtin_amdgcn_mfma_f32_32x32x16_bf16(A0, vfa5, acc[5], 0, 0, 0);
        acc[5] = __builtin_amdgcn_mfma_f32_32x32x16_bf16(A1, vfb5, acc[5], 0, 0, 0);
        acc[6] = __builtin_amdgcn_mfma_f32_32x32x16_bf16(A0, vfa6, acc[6], 0, 0, 0);
        acc[6] = __builtin_amdgcn_mfma_f32_32x32x16_bf16(A1, vfb6, acc[6], 0, 0, 0);
        acc[7] = __builtin_amdgcn_mfma_f32_32x32x16_bf16(A0, vfa7, acc[7], 0, 0, 0);
        acc[7] = __builtin_amdgcn_mfma_f32_32x32x16_bf16(A1, vfb7, acc[7], 0, 0, 0);
#pragma unroll
        for (int cg = 0; cg < 8; ++cg) vp[cg] += 1024;
    }

    // l: combine lane halves (disjoint kcol rows), then sum the 4 k-quarters
    lsum += __shfl_xor(lsum, 32, 64);
    if (lh == 0) lpart[wv_][l31] = lsum;
    __syncthreads();

    int j31r = tid & 31;
    int cgrp = tid >> 5;   // 0..7 -> 4 c-rows each
    float gl = gamma_p[0] /
               (lpart[0][j31r] + lpart[1][j31r] + lpart[2][j31r] + lpart[3][j31r]);
    const float* xbb = x + (size_t)b * CC * NN;
    float* obb = out + (size_t)b * CC * NN;
    int hofs = lh * 4;
    // O reduction over the 4 k-quarter waves, one cg (32c) tile at a time.
#pragma unroll
    for (int cg = 0; cg < 8; ++cg) {
        __syncthreads();
#pragma unroll
        for (int r = 0; r < 16; ++r) {
            int row = (r & 3) + 8 * (r >> 2) + hofs;
            obuf[wv_][row][l31] = acc[cg][r];
        }
        __syncthreads();
#pragma unroll
        for (int i = 0; i < 4; ++i) {
            int c = cgrp * 4 + i;
            float val = obuf[0][j31r][c] + obuf[1][j31r][c] + obuf[2][j31r][c] + obuf[3][j31r][c];
            size_t oidx = (size_t)(cg * 32 + c) * NN + jbase + j31r;
            obb[oidx] = fmaf(gl, val, xbb[oidx]);
        }
    }
}

extern "C" void kernel_launch(void* const* d_in, const int* in_sizes, int n_in,
                              void* d_out, int out_size, void* d_ws, size_t ws_size,
                              hipStream_t stream) {
    const float* x     = (const float*)d_in[0];
    const float* wq    = (const float*)d_in[1];
    const float* bq    = (const float*)d_in[2];
    const float* wk    = (const float*)d_in[3];
    const float* bk    = (const float*)d_in[4];
    const float* wv    = (const float*)d_in[5];
    const float* bv    = (const float*)d_in[6];
    const float* gamma = (const float*)d_in[7];
    const float* eps_q = (const float*)d_in[8];
    const float* eps_k = (const float*)d_in[9];
    float* out = (float*)d_out;

    char* ws = (char*)d_ws;
    unsigned short* qrawh = (unsigned short*)ws;                     // 512 KB (1 MB slot)
    unsigned short* krawh = (unsigned short*)(ws + (1u << 20));      // 512 KB (1 MB slot)
    float* nu2  = (float*)(ws + (2u << 20));                         // 512 B
    unsigned short* qb = (unsigned short*)(ws + (2u << 20) + 4096);  // 512 KB
    unsigned short* kb = qb + (size_t)NB * NN * C16;                 // 512 KB
    unsigned short* vb = kb + (size_t)NB * NN * C16;                 // 8 MB
    unsigned short* xT = vb + (size_t)NB * CC * NN;                  // 8 MB
    unsigned short* wvb = xT + (size_t)NB * NN * CC;                 // 128 KB
    unsigned short* wqkb = wvb + (size_t)CC * CC;                    // 48 KB

    prep_kernel<<<dim3(1112), dim3(256), 0, stream>>>(x, wv, wq, wk, xT, wvb, wqkb, nu2);
    conv_kernel<<<dim3(768), dim3(256), 0, stream>>>(xT, wvb, wqkb, bv, bq, bk, vb, qrawh, krawh, nu2);
    frn_mish_kernel<<<dim3(512), dim3(256), 0, stream>>>(qrawh, krawh, nu2, eps_q, eps_k, qb, kb);
    attn_kernel<<<dim3(512), dim3(256), 0, stream>>>(qb, kb, vb, x, gamma, out);
}